// Round 14
// baseline (360.802 us; speedup 1.0000x reference)
//
#include <hip/hip_runtime.h>

typedef unsigned short u16;
typedef unsigned int   u32;
typedef __attribute__((ext_vector_type(8))) _Float16 half8;
typedef __attribute__((ext_vector_type(4))) float f32x4;
typedef __attribute__((ext_vector_type(2))) float f32x2;
typedef __attribute__((ext_vector_type(4))) u32   u32x4;
typedef __attribute__((ext_vector_type(4))) unsigned short u16x4;

#define MFMAH __builtin_amdgcn_mfma_f32_16x16x32_f16

// W fp16 storage: rows 0-511 = Wf, 512-1023 = Wg, 1024-1535 = Wh, k-contig.
__device__ u16 W16[786432];

__device__ __forceinline__ u16 f2h(float f) {            // fp32 -> fp16 rne
  _Float16 h = (_Float16)f;
  union { _Float16 hh; u16 u; } cv; cv.hh = h; return cv.u;
}
__device__ __forceinline__ u32 pkh(float a, float b) {   // two rne halves packed
  return (u32)f2h(a) | ((u32)f2h(b) << 16);
}
__device__ __forceinline__ void gload16(const void* g, void* l) {
  __builtin_amdgcn_global_load_lds(
      (const __attribute__((address_space(1))) void*)g,
      (__attribute__((address_space(3))) void*)l, 16, 0, 0);
}

// ---------------------------------------------------------------------------
// prep_w: W fp32 -> fp16 (rne)
// ---------------------------------------------------------------------------
__global__ __launch_bounds__(256)
void prep_w(const float* __restrict__ Wf, const float* __restrict__ Wg,
            const float* __restrict__ Wh)
{
  const int r = blockIdx.x;                    // 0..1535
  const int k = threadIdx.x * 2;
  const float* src = (r < 512) ? (Wf + (size_t)r * 512)
                   : (r < 1024) ? (Wg + (size_t)(r - 512) * 512)
                                : (Wh + (size_t)(r - 1024) * 512);
  f32x2 v = *(const f32x2*)(src + k);
  *(u32*)(W16 + (size_t)r * 512 + k) = pkh(v[0], v[1]);
}

// ---------------------------------------------------------------------------
// prep_x: x[512][65536] fp32 -> xT[65536][512] fp16 (rne).
// ---------------------------------------------------------------------------
__global__ __launch_bounds__(256)
void prep_x(const float* __restrict__ x, u16* __restrict__ x16)
{
  __shared__ float tile[64 * 256];             // 64 KB
  const int bk = blockIdx.x & 7, bn = blockIdx.x >> 3;
  const int t = threadIdx.x;
  const int cw = (t & 63) * 4, r0 = (t >> 6) * 16;
#pragma unroll
  for (int it = 0; it < 16; ++it) {
    const int r = r0 + it;
    *(f32x4*)&tile[r * 256 + cw] =
        *(const f32x4*)(x + (size_t)(bk * 64 + r) * 65536 + (size_t)bn * 256 + cw);
  }
  __syncthreads();
  u32 w[32];
#pragma unroll
  for (int q = 0; q < 32; ++q)
    w[q] = pkh(tile[(2 * q) * 256 + t], tile[(2 * q + 1) * 256 + t]);
  const size_t ob = (size_t)(bn * 256 + t) * 512 + bk * 64;
#pragma unroll
  for (int c4 = 0; c4 < 8; ++c4)
    *(u32x4*)(x16 + ob + c4 * 8) = (u32x4){w[4*c4], w[4*c4+1], w[4*c4+2], w[4*c4+3]};
}

// ---------------------------------------------------------------------------
// conv_fgh: fused fp16 GEMM, M=1536 ([f;g;h] = W @ x). 128x128 tile, BK=64,
// 256 thr / 4 waves (2x2). Proven 184 us plateau structure (r13).
// ---------------------------------------------------------------------------
__global__ __launch_bounds__(256)
void conv_fgh(const u16* __restrict__ x16, u16* __restrict__ fb,
              u16* __restrict__ gTb, u16* __restrict__ hb)
{
  __shared__ u16 sA[8192], sB[8192];           // 16 KB each: 128 rows x 64 k
  const int bid = blockIdx.x;
  const int xcd = bid & 7, idx = bid >> 3;     // 6144 = 8 XCD x (64 tn x 12 tm)
  const int tn = xcd * 64 + idx / 12;
  const int tm = idx % 12;
  const bool gmode = (tm >= 4) && (tm < 8);
  const int t = threadIdx.x, lane = t & 63, wid = t >> 6;
  const int wr = wid >> 1, wc = wid & 1, lr = lane & 15, lq = lane >> 4;

  const int srow = t >> 3, sslot = t & 7;      // srow 0..31 within chunk
  int arow_g[4]; size_t bxr_g[4]; int ksw[4];
#pragma unroll
  for (int q = 0; q < 4; ++q) {
    const int row = q * 32 + srow;             // 0..127
    ksw[q] = ((sslot ^ (row & 7)) << 3);
    arow_g[q] = tm * 128 + row;
    const int jg = tn * 128 + row;
    bxr_g[q] = gmode ? ((size_t)(jg & 255) * 256 + (jg >> 8)) : (size_t)jg;
  }

  int offA[4], a7[4], offB[4], b7[4];
#pragma unroll
  for (int mi = 0; mi < 4; ++mi) {
    const int rowA = wr * 64 + mi * 16 + lr;
    offA[mi] = rowA * 64; a7[mi] = rowA & 7;
  }
#pragma unroll
  for (int ni = 0; ni < 4; ++ni) {
    const int rowB = wc * 64 + ni * 16 + lr;
    offB[ni] = rowB * 64; b7[ni] = rowB & 7;
  }

  f32x4 acc[4][4] = {};

  for (int k0 = 0; k0 < 512; k0 += 64) {
#pragma unroll
    for (int q = 0; q < 4; ++q) {
      gload16(W16 + (size_t)arow_g[q] * 512 + k0 + ksw[q], (char*)sA + q * 4096 + t * 16);
      gload16(x16 + bxr_g[q] * 512 + k0 + ksw[q],          (char*)sB + q * 4096 + t * 16);
    }
    __syncthreads();
#pragma unroll
    for (int kk = 0; kk < 2; ++kk) {
      half8 a[4], b[4];
#pragma unroll
      for (int mi = 0; mi < 4; ++mi)
        a[mi] = *(const half8*)(sA + offA[mi] + (((kk * 4 + lq) ^ a7[mi]) << 3));
#pragma unroll
      for (int ni = 0; ni < 4; ++ni)
        b[ni] = *(const half8*)(sB + offB[ni] + (((kk * 4 + lq) ^ b7[ni]) << 3));
#pragma unroll
      for (int mi = 0; mi < 4; ++mi)
#pragma unroll
        for (int ni = 0; ni < 4; ++ni)
          acc[mi][ni] = MFMAH(a[mi], b[ni], acc[mi][ni], 0, 0, 0);
    }
    __syncthreads();
  }

  const int cls = tm >> 2;                     // 0:f 1:g 2:h
  u16* dst = (cls == 0) ? fb : (cls == 1) ? gTb : hb;
  const int rbase = (tm & 3) * 128 + wr * 64;
  const int cbase = tn * 128 + wc * 64;
#pragma unroll
  for (int mi = 0; mi < 4; ++mi)
#pragma unroll
    for (int ni = 0; ni < 4; ++ni) {
      const int r0 = rbase + mi * 16 + lq * 4;
      const int cc = cbase + ni * 16 + lr;
#pragma unroll
      for (int r = 0; r < 4; ++r)
        dst[(size_t)(r0 + r) * 65536 + cc] = f2h(acc[mi][ni][r]);
    }
}

// ---------------------------------------------------------------------------
// fused_sa: one block per channel (512 thr, 8 waves 2x4, 160 KB LDS).
// Phase 1: S = f[c] @ gT[c]^T (256x256, acc1[8][4]); full-column softmax;
//          P^T[j][i] fp16 -> RESIDENT LDS (128 KB, granule-XOR swizzled).
// Phase 2: out = x + h[c] @ P^T; h staged into the dead f-staging slot;
//          B-frags read from resident P^T. P never touches HBM.
// LDS: P^T [0,128K); sF [128K,144K); sG [144K,160K); stats alias sG.
// ---------------------------------------------------------------------------
__global__ __launch_bounds__(512, 2)
void fused_sa(const u16* __restrict__ fb, const u16* __restrict__ gTb,
              const u16* __restrict__ hb, const float* __restrict__ x,
              float* __restrict__ out)
{
  __shared__ u16 lds[81920];                   // 160 KB
  char* const L = (char*)lds;
  float* const cmax = (float*)(L + 147456);    // 2 KB (aliases sG, dead then)
  float* const csum = (float*)(L + 149504);    // 2 KB
  const int bid = blockIdx.x;
  const int c = (bid & 7) * 64 + (bid >> 3);   // XCD-chunked, 512%8==0
  const size_t cb = (size_t)c * 65536;
  const int t = threadIdx.x, lane = t & 63, wid = t >> 6;
  const int wr = wid >> 2, wc = wid & 3, lr = lane & 15, lq = lane >> 4;

  // staging chunks: e = q*512+t -> row = e>>2 (0..255), slot = e&3
  const int r0s = t >> 2, r1s = 128 + (t >> 2);
  const int ks0 = (((t & 3) ^ ((r0s >> 1) & 3)) << 3);
  const int ks1 = (((t & 3) ^ ((r1s >> 1) & 3)) << 3);

  // A-frag offsets (rows 0..255 in sF @128K, 64 B rows, proven swizzle)
  int offA[8];
#pragma unroll
  for (int mi = 0; mi < 8; ++mi) {
    const int rowA = wr * 128 + mi * 16 + lr;
    offA[mi] = 131072 + rowA * 64 + ((lq ^ ((rowA >> 1) & 3)) << 4);
  }
  // B-frag offsets phase1 (rows 0..255 in sG @144K)
  int offB[4], jcol[4], ej[4];
#pragma unroll
  for (int ni = 0; ni < 4; ++ni) {
    const int rowB = wc * 64 + ni * 16 + lr;
    offB[ni] = 147456 + rowB * 64 + ((lq ^ ((rowB >> 1) & 3)) << 4);
    jcol[ni] = rowB;                           // column j this lane owns
    ej[ni] = (rowB & 7) << 1;                  // P^T granule XOR key (even)
  }

  // ================= phase 1: scores =================
  f32x4 acc1[8][4] = {};
  for (int k0 = 0; k0 < 256; k0 += 32) {
    gload16(fb + cb + (size_t)r0s * 256 + k0 + ks0, L + 131072 + t * 16);
    gload16(fb + cb + (size_t)r1s * 256 + k0 + ks1, L + 139264 + t * 16);
    gload16(gTb + cb + (size_t)r0s * 256 + k0 + ks0, L + 147456 + t * 16);
    gload16(gTb + cb + (size_t)r1s * 256 + k0 + ks1, L + 155648 + t * 16);
    __syncthreads();
    half8 b[4];
#pragma unroll
    for (int ni = 0; ni < 4; ++ni) b[ni] = *(const half8*)(L + offB[ni]);
#pragma unroll
    for (int mi = 0; mi < 8; ++mi) {
      half8 a = *(const half8*)(L + offA[mi]);
#pragma unroll
      for (int ni = 0; ni < 4; ++ni)
        acc1[mi][ni] = MFMAH(a, b[ni], acc1[mi][ni], 0, 0, 0);
    }
    __syncthreads();
  }

  // ---- full-column softmax (rows i span wr,mi,lq,r; column j per ni,lr)
#pragma unroll
  for (int ni = 0; ni < 4; ++ni) {
    float m = -3.4e38f;
#pragma unroll
    for (int mi = 0; mi < 8; ++mi) {
      f32x4 a = acc1[mi][ni];
      m = fmaxf(m, fmaxf(fmaxf(a[0], a[1]), fmaxf(a[2], a[3])));
    }
    m = fmaxf(m, __shfl_xor(m, 16));
    m = fmaxf(m, __shfl_xor(m, 32));
    cmax[wr * 256 + jcol[ni]] = m;
  }
  __syncthreads();
  float rsv[4];
#pragma unroll
  for (int ni = 0; ni < 4; ++ni) {
    const int j = jcol[ni];
    const float M = fmaxf(cmax[j], cmax[256 + j]);
    float s = 0.f;
#pragma unroll
    for (int mi = 0; mi < 8; ++mi)
#pragma unroll
      for (int r = 0; r < 4; ++r) {
        float e = __expf(acc1[mi][ni][r] - M);
        acc1[mi][ni][r] = e; s += e;
      }
    s += __shfl_xor(s, 16);
    s += __shfl_xor(s, 32);
    csum[wr * 256 + jcol[ni]] = s;
  }
  __syncthreads();
#pragma unroll
  for (int ni = 0; ni < 4; ++ni)
    rsv[ni] = 1.f / (csum[jcol[ni]] + csum[256 + jcol[ni]]);
  __syncthreads();                             // stats read done; sG reusable

  // ---- write P^T[j][i] fp16 into LDS [0,128K), granule-swizzled.
  // granule g = i>>2 (8 B); byte = j*512 + ((g ^ ej)<<3). i = wr*128+mi*16+lq*4+r.
#pragma unroll
  for (int ni = 0; ni < 4; ++ni) {
    const int jb = jcol[ni] * 512;
#pragma unroll
    for (int mi = 0; mi < 8; ++mi) {
      const int g = wr * 32 + mi * 4 + lq;     // i>>2
      u16x4 w = { f2h(acc1[mi][ni][0] * rsv[ni]), f2h(acc1[mi][ni][1] * rsv[ni]),
                  f2h(acc1[mi][ni][2] * rsv[ni]), f2h(acc1[mi][ni][3] * rsv[ni]) };
      *(u16x4*)(L + jb + ((g ^ ej[ni]) << 3)) = w;
    }
  }
  __syncthreads();                             // P^T resident & visible

  // ================= phase 2: attn =================
  f32x4 acc2[8][4] = {};
  for (int k0 = 0; k0 < 256; k0 += 32) {
    gload16(hb + cb + (size_t)r0s * 256 + k0 + ks0, L + 131072 + t * 16);
    gload16(hb + cb + (size_t)r1s * 256 + k0 + ks1, L + 139264 + t * 16);
    __syncthreads();
    half8 b2[4];
#pragma unroll
    for (int ni = 0; ni < 4; ++ni) {
      const int g2 = (k0 >> 2) + lq * 2;       // even granule index
      b2[ni] = *(const half8*)(L + jcol[ni] * 512 + ((g2 ^ ej[ni]) << 3));
    }
#pragma unroll
    for (int mi = 0; mi < 8; ++mi) {
      half8 a = *(const half8*)(L + offA[mi]); // h rows, same staging layout
#pragma unroll
      for (int ni = 0; ni < 4; ++ni)
        acc2[mi][ni] = MFMAH(a, b2[ni], acc2[mi][ni], 0, 0, 0);
    }
    __syncthreads();
  }

  // ---- epilogue: out = x + acc2
  const float* Xc = x + cb;
  float* Oc = out + cb;
#pragma unroll
  for (int mi = 0; mi < 8; ++mi)
#pragma unroll
    for (int ni = 0; ni < 4; ++ni) {
      const int a0 = wr * 128 + mi * 16 + lq * 4;
      const int j = jcol[ni];
#pragma unroll
      for (int r = 0; r < 4; ++r) {
        const size_t idx = (size_t)(a0 + r) * 256 + j;
        Oc[idx] = Xc[idx] + acc2[mi][ni][r];
      }
    }
}

// ---------------------------------------------------------------------------
extern "C" void kernel_launch(void* const* d_in, const int* in_sizes, int n_in,
                              void* d_out, int out_size, void* d_ws, size_t ws_size,
                              hipStream_t stream)
{
  (void)in_sizes; (void)n_in; (void)out_size; (void)ws_size;
  const float* x  = (const float*)d_in[0];
  const float* Wf = (const float*)d_in[1];
  const float* Wg = (const float*)d_in[2];
  const float* Wh = (const float*)d_in[3];
  float* out = (float*)d_out;
  char*  ws  = (char*)d_ws;

  // ws (256 MiB): [x16 64Mi][gT16 64Mi][h16 64Mi][f16 64Mi]. No d_out aliasing.
  u16* x16  = (u16*)ws;
  u16* gT16 = (u16*)(ws + 67108864);
  u16* h16  = (u16*)(ws + 134217728);
  u16* f16  = (u16*)(ws + 201326592);

  dim3 blk(256, 1, 1);
  prep_w  <<<dim3(1536, 1, 1), blk, 0, stream>>>(Wf, Wg, Wh);
  prep_x  <<<dim3(2048, 1, 1), blk, 0, stream>>>(x, x16);
  conv_fgh<<<dim3(6144, 1, 1), blk, 0, stream>>>(x16, f16, gT16, h16);
  fused_sa<<<dim3(512, 1, 1), dim3(512, 1, 1), 0, stream>>>(f16, gT16, h16, x, out);
}

// Round 15
// 348.639 us; speedup vs baseline: 1.0349x; 1.0349x over previous
//
#include <hip/hip_runtime.h>

typedef unsigned short u16;
typedef unsigned int   u32;
typedef __attribute__((ext_vector_type(8))) _Float16 half8;
typedef __attribute__((ext_vector_type(4))) float f32x4;
typedef __attribute__((ext_vector_type(2))) float f32x2;
typedef __attribute__((ext_vector_type(4))) u32   u32x4;
typedef __attribute__((ext_vector_type(4))) unsigned short u16x4;

#define MFMAH __builtin_amdgcn_mfma_f32_16x16x32_f16

// W fp16 storage: rows 0-511 = Wf, 512-1023 = Wg, 1024-1535 = Wh, k-contig.
__device__ u16 W16[786432];

__device__ __forceinline__ u16 f2h(float f) {            // fp32 -> fp16 rne
  _Float16 h = (_Float16)f;
  union { _Float16 hh; u16 u; } cv; cv.hh = h; return cv.u;
}
__device__ __forceinline__ u32 pkh(float a, float b) {   // two rne halves packed
  return (u32)f2h(a) | ((u32)f2h(b) << 16);
}
__device__ __forceinline__ void gload16(const void* g, void* l) {
  __builtin_amdgcn_global_load_lds(
      (const __attribute__((address_space(1))) void*)g,
      (__attribute__((address_space(3))) void*)l, 16, 0, 0);
}

// ---------------------------------------------------------------------------
// prep_w: W fp32 -> fp16 (rne)
// ---------------------------------------------------------------------------
__global__ __launch_bounds__(256)
void prep_w(const float* __restrict__ Wf, const float* __restrict__ Wg,
            const float* __restrict__ Wh)
{
  const int r = blockIdx.x;                    // 0..1535
  const int k = threadIdx.x * 2;
  const float* src = (r < 512) ? (Wf + (size_t)r * 512)
                   : (r < 1024) ? (Wg + (size_t)(r - 512) * 512)
                                : (Wh + (size_t)(r - 1024) * 512);
  f32x2 v = *(const f32x2*)(src + k);
  *(u32*)(W16 + (size_t)r * 512 + k) = pkh(v[0], v[1]);
}

// ---------------------------------------------------------------------------
// prep_x: x[512][65536] fp32 -> xT[65536][512] fp16 (rne).
// ---------------------------------------------------------------------------
__global__ __launch_bounds__(256)
void prep_x(const float* __restrict__ x, u16* __restrict__ x16)
{
  __shared__ float tile[64 * 256];             // 64 KB
  const int bk = blockIdx.x & 7, bn = blockIdx.x >> 3;
  const int t = threadIdx.x;
  const int cw = (t & 63) * 4, r0 = (t >> 6) * 16;
#pragma unroll
  for (int it = 0; it < 16; ++it) {
    const int r = r0 + it;
    *(f32x4*)&tile[r * 256 + cw] =
        *(const f32x4*)(x + (size_t)(bk * 64 + r) * 65536 + (size_t)bn * 256 + cw);
  }
  __syncthreads();
  u32 w[32];
#pragma unroll
  for (int q = 0; q < 32; ++q)
    w[q] = pkh(tile[(2 * q) * 256 + t], tile[(2 * q + 1) * 256 + t]);
  const size_t ob = (size_t)(bn * 256 + t) * 512 + bk * 64;
#pragma unroll
  for (int c4 = 0; c4 < 8; ++c4)
    *(u32x4*)(x16 + ob + c4 * 8) = (u32x4){w[4*c4], w[4*c4+1], w[4*c4+2], w[4*c4+3]};
}

// ---------------------------------------------------------------------------
// conv_fgh: fused fp16 GEMM, M=1536 ([f;g;h] = W @ x). 128x128 tile, BK=64,
// 256 thr / 4 waves (2x2). Proven plateau structure (r13).
// f output is INTERLEAVED into d_out: channel row stride 131072 u16
// (first half of each out[c] 256 KB slot) -> de-aliases the HBM channels.
// ---------------------------------------------------------------------------
__global__ __launch_bounds__(256)
void conv_fgh(const u16* __restrict__ x16, u16* __restrict__ fb,
              u16* __restrict__ gTb, u16* __restrict__ hb)
{
  __shared__ u16 sA[8192], sB[8192];           // 16 KB each: 128 rows x 64 k
  const int bid = blockIdx.x;
  const int xcd = bid & 7, idx = bid >> 3;     // 6144 = 8 XCD x (64 tn x 12 tm)
  const int tn = xcd * 64 + idx / 12;
  const int tm = idx % 12;
  const bool gmode = (tm >= 4) && (tm < 8);
  const int t = threadIdx.x, lane = t & 63, wid = t >> 6;
  const int wr = wid >> 1, wc = wid & 1, lr = lane & 15, lq = lane >> 4;

  const int srow = t >> 3, sslot = t & 7;      // srow 0..31 within chunk
  int arow_g[4]; size_t bxr_g[4]; int ksw[4];
#pragma unroll
  for (int q = 0; q < 4; ++q) {
    const int row = q * 32 + srow;             // 0..127
    ksw[q] = ((sslot ^ (row & 7)) << 3);
    arow_g[q] = tm * 128 + row;
    const int jg = tn * 128 + row;
    bxr_g[q] = gmode ? ((size_t)(jg & 255) * 256 + (jg >> 8)) : (size_t)jg;
  }

  int offA[4], a7[4], offB[4], b7[4];
#pragma unroll
  for (int mi = 0; mi < 4; ++mi) {
    const int rowA = wr * 64 + mi * 16 + lr;
    offA[mi] = rowA * 64; a7[mi] = rowA & 7;
  }
#pragma unroll
  for (int ni = 0; ni < 4; ++ni) {
    const int rowB = wc * 64 + ni * 16 + lr;
    offB[ni] = rowB * 64; b7[ni] = rowB & 7;
  }

  f32x4 acc[4][4] = {};

  for (int k0 = 0; k0 < 512; k0 += 64) {
#pragma unroll
    for (int q = 0; q < 4; ++q) {
      gload16(W16 + (size_t)arow_g[q] * 512 + k0 + ksw[q], (char*)sA + q * 4096 + t * 16);
      gload16(x16 + bxr_g[q] * 512 + k0 + ksw[q],          (char*)sB + q * 4096 + t * 16);
    }
    __syncthreads();
#pragma unroll
    for (int kk = 0; kk < 2; ++kk) {
      half8 a[4], b[4];
#pragma unroll
      for (int mi = 0; mi < 4; ++mi)
        a[mi] = *(const half8*)(sA + offA[mi] + (((kk * 4 + lq) ^ a7[mi]) << 3));
#pragma unroll
      for (int ni = 0; ni < 4; ++ni)
        b[ni] = *(const half8*)(sB + offB[ni] + (((kk * 4 + lq) ^ b7[ni]) << 3));
#pragma unroll
      for (int mi = 0; mi < 4; ++mi)
#pragma unroll
        for (int ni = 0; ni < 4; ++ni)
          acc[mi][ni] = MFMAH(a[mi], b[ni], acc[mi][ni], 0, 0, 0);
    }
    __syncthreads();
  }

  const int cls = tm >> 2;                     // 0:f 1:g 2:h
  u16* dst = (cls == 0) ? fb : (cls == 1) ? gTb : hb;
  const size_t dstride = (cls == 0) ? 131072 : 65536;  // f interleaved in d_out
  const int rbase = (tm & 3) * 128 + wr * 64;
  const int cbase = tn * 128 + wc * 64;
#pragma unroll
  for (int mi = 0; mi < 4; ++mi)
#pragma unroll
    for (int ni = 0; ni < 4; ++ni) {
      const int r0 = rbase + mi * 16 + lq * 4;
      const int cc = cbase + ni * 16 + lr;
#pragma unroll
      for (int r = 0; r < 4; ++r)
        dst[(size_t)(r0 + r) * dstride + cc] = f2h(acc[mi][ni][r]);
    }
}

// ---------------------------------------------------------------------------
// fused_sa: one block per channel (512 thr, 8 waves 2x4, 160 KB LDS).
// Phase 1: S = f[c] @ gT[c]^T; full-column softmax; P^T fp16 -> resident LDS.
// Phase 2: out = x + h[c] @ P^T. f16 read from d_out (interleaved, own-slot,
// read strictly before own-slot out write -> race-free). h tile-0 prefetched
// during the softmax VALU section.
// LDS: P^T [0,128K); sF [128K,144K); sG [144K,160K); stats alias sG.
// ---------------------------------------------------------------------------
__global__ __launch_bounds__(512, 2)
void fused_sa(const u16* __restrict__ fb, const u16* __restrict__ gTb,
              const u16* __restrict__ hb, const float* __restrict__ x,
              float* __restrict__ out)
{
  __shared__ u16 lds[81920];                   // 160 KB
  char* const L = (char*)lds;
  float* const cmax = (float*)(L + 147456);    // 2 KB (aliases sG, dead then)
  float* const csum = (float*)(L + 149504);    // 2 KB
  const int bid = blockIdx.x;
  const int c = (bid & 7) * 64 + (bid >> 3);   // XCD-chunked, 512%8==0
  const size_t cb = (size_t)c * 65536;
  const size_t cbf = (size_t)c * 131072;       // f16 interleaved channel base
  const int t = threadIdx.x, lane = t & 63, wid = t >> 6;
  const int wr = wid >> 2, wc = wid & 3, lr = lane & 15, lq = lane >> 4;

  // staging chunks: e = q*512+t -> row = e>>2 (0..255), slot = e&3
  const int r0s = t >> 2, r1s = 128 + (t >> 2);
  const int ks0 = (((t & 3) ^ ((r0s >> 1) & 3)) << 3);
  const int ks1 = (((t & 3) ^ ((r1s >> 1) & 3)) << 3);

  // A-frag offsets (rows 0..255 in sF @128K, 64 B rows, proven swizzle)
  int offA[8];
#pragma unroll
  for (int mi = 0; mi < 8; ++mi) {
    const int rowA = wr * 128 + mi * 16 + lr;
    offA[mi] = 131072 + rowA * 64 + ((lq ^ ((rowA >> 1) & 3)) << 4);
  }
  // B-frag offsets phase1 (rows 0..255 in sG @144K)
  int offB[4], jcol[4], ej[4];
#pragma unroll
  for (int ni = 0; ni < 4; ++ni) {
    const int rowB = wc * 64 + ni * 16 + lr;
    offB[ni] = 147456 + rowB * 64 + ((lq ^ ((rowB >> 1) & 3)) << 4);
    jcol[ni] = rowB;                           // column j this lane owns
    ej[ni] = (rowB & 7) << 1;                  // P^T granule XOR key (even)
  }

  // ================= phase 1: scores =================
  f32x4 acc1[8][4] = {};
  for (int k0 = 0; k0 < 256; k0 += 32) {
    gload16(fb + cbf + (size_t)r0s * 256 + k0 + ks0, L + 131072 + t * 16);
    gload16(fb + cbf + (size_t)r1s * 256 + k0 + ks1, L + 139264 + t * 16);
    gload16(gTb + cb + (size_t)r0s * 256 + k0 + ks0, L + 147456 + t * 16);
    gload16(gTb + cb + (size_t)r1s * 256 + k0 + ks1, L + 155648 + t * 16);
    __syncthreads();
    half8 b[4];
#pragma unroll
    for (int ni = 0; ni < 4; ++ni) b[ni] = *(const half8*)(L + offB[ni]);
#pragma unroll
    for (int mi = 0; mi < 8; ++mi) {
      half8 a = *(const half8*)(L + offA[mi]);
#pragma unroll
      for (int ni = 0; ni < 4; ++ni)
        acc1[mi][ni] = MFMAH(a, b[ni], acc1[mi][ni], 0, 0, 0);
    }
    __syncthreads();
  }

  // prefetch h tile-0 into sF (dead after phase-1); drains under softmax
  gload16(hb + cb + (size_t)r0s * 256 + ks0, L + 131072 + t * 16);
  gload16(hb + cb + (size_t)r1s * 256 + ks1, L + 139264 + t * 16);

  // ---- full-column softmax (rows i span wr,mi,lq,r; column j per ni,lr)
#pragma unroll
  for (int ni = 0; ni < 4; ++ni) {
    float m = -3.4e38f;
#pragma unroll
    for (int mi = 0; mi < 8; ++mi) {
      f32x4 a = acc1[mi][ni];
      m = fmaxf(m, fmaxf(fmaxf(a[0], a[1]), fmaxf(a[2], a[3])));
    }
    m = fmaxf(m, __shfl_xor(m, 16));
    m = fmaxf(m, __shfl_xor(m, 32));
    cmax[wr * 256 + jcol[ni]] = m;
  }
  __syncthreads();
  float rsv[4];
#pragma unroll
  for (int ni = 0; ni < 4; ++ni) {
    const int j = jcol[ni];
    const float M = fmaxf(cmax[j], cmax[256 + j]);
    float s = 0.f;
#pragma unroll
    for (int mi = 0; mi < 8; ++mi)
#pragma unroll
      for (int r = 0; r < 4; ++r) {
        float e = __expf(acc1[mi][ni][r] - M);
        acc1[mi][ni][r] = e; s += e;
      }
    s += __shfl_xor(s, 16);
    s += __shfl_xor(s, 32);
    csum[wr * 256 + jcol[ni]] = s;
  }
  __syncthreads();
#pragma unroll
  for (int ni = 0; ni < 4; ++ni)
    rsv[ni] = 1.f / (csum[jcol[ni]] + csum[256 + jcol[ni]]);
  __syncthreads();                             // stats read done

  // ---- write P^T[j][i] fp16 into LDS [0,128K), granule-swizzled.
#pragma unroll
  for (int ni = 0; ni < 4; ++ni) {
    const int jb = jcol[ni] * 512;
#pragma unroll
    for (int mi = 0; mi < 8; ++mi) {
      const int g = wr * 32 + mi * 4 + lq;     // i>>2
      u16x4 w = { f2h(acc1[mi][ni][0] * rsv[ni]), f2h(acc1[mi][ni][1] * rsv[ni]),
                  f2h(acc1[mi][ni][2] * rsv[ni]), f2h(acc1[mi][ni][3] * rsv[ni]) };
      *(u16x4*)(L + jb + ((g ^ ej[ni]) << 3)) = w;
    }
  }
  __syncthreads();                             // P^T visible + h tile-0 landed

  // ================= phase 2: attn =================
  f32x4 acc2[8][4] = {};
  for (int k0 = 0; k0 < 256; k0 += 32) {
    if (k0) {
      gload16(hb + cb + (size_t)r0s * 256 + k0 + ks0, L + 131072 + t * 16);
      gload16(hb + cb + (size_t)r1s * 256 + k0 + ks1, L + 139264 + t * 16);
      __syncthreads();
    }
    half8 b2[4];
#pragma unroll
    for (int ni = 0; ni < 4; ++ni) {
      const int g2 = (k0 >> 2) + lq * 2;       // even granule index
      b2[ni] = *(const half8*)(L + jcol[ni] * 512 + ((g2 ^ ej[ni]) << 3));
    }
#pragma unroll
    for (int mi = 0; mi < 8; ++mi) {
      half8 a = *(const half8*)(L + offA[mi]); // h rows, same staging layout
#pragma unroll
      for (int ni = 0; ni < 4; ++ni)
        acc2[mi][ni] = MFMAH(a, b2[ni], acc2[mi][ni], 0, 0, 0);
    }
    __syncthreads();
  }

  // ---- epilogue: out = x + acc2 (own-slot write; f16 reads all done)
  const float* Xc = x + cb;
  float* Oc = out + cb;
#pragma unroll
  for (int mi = 0; mi < 8; ++mi)
#pragma unroll
    for (int ni = 0; ni < 4; ++ni) {
      const int a0 = wr * 128 + mi * 16 + lq * 4;
      const int j = jcol[ni];
#pragma unroll
      for (int r = 0; r < 4; ++r) {
        const size_t idx = (size_t)(a0 + r) * 256 + j;
        Oc[idx] = Xc[idx] + acc2[mi][ni][r];
      }
    }
}

// ---------------------------------------------------------------------------
extern "C" void kernel_launch(void* const* d_in, const int* in_sizes, int n_in,
                              void* d_out, int out_size, void* d_ws, size_t ws_size,
                              hipStream_t stream)
{
  (void)in_sizes; (void)n_in; (void)out_size; (void)ws_size;
  const float* x  = (const float*)d_in[0];
  const float* Wf = (const float*)d_in[1];
  const float* Wg = (const float*)d_in[2];
  const float* Wh = (const float*)d_in[3];
  float* out = (float*)d_out;
  char*  ws  = (char*)d_ws;

  // Buffers de-aliased: x16 @ws, gT @ws+64Mi+64K, h @ws+128Mi+128K;
  // f16 interleaved in d_out (channel c at byte c*262144, 128 KB used).
  u16* x16  = (u16*)ws;
  u16* gT16 = (u16*)(ws + 67108864 + 65536);
  u16* h16  = (u16*)(ws + 134217728 + 131072);
  u16* f16  = (u16*)d_out;

  dim3 blk(256, 1, 1);
  prep_w  <<<dim3(1536, 1, 1), blk, 0, stream>>>(Wf, Wg, Wh);
  prep_x  <<<dim3(2048, 1, 1), blk, 0, stream>>>(x, x16);
  conv_fgh<<<dim3(6144, 1, 1), blk, 0, stream>>>(x16, f16, gT16, h16);
  fused_sa<<<dim3(512, 1, 1), dim3(512, 1, 1), 0, stream>>>(f16, gT16, h16, x, out);
}